// Round 1
// baseline (135823.657 us; speedup 1.0000x reference)
//
#include <hip/hip_runtime.h>
#include <math.h>

typedef float f4 __attribute__((ext_vector_type(4)));

#define Hdim 2048
#define Bdim 256
#define Tdim 512
#define Odim 14
#define G3   6144   // 3*Hdim

// ---------------------------------------------------------------------------
// Prep kernels (run once per launch; ws is re-poisoned before every call)
// ---------------------------------------------------------------------------

// Gtable[c][row], c in 0..14: gi row for one-hot input c (c==14 -> dead, x=0)
__global__ void prep_gtable(const float* __restrict__ b_ih,
                            const float* __restrict__ W_ih,
                            float* __restrict__ Gt) {
    int idx = blockIdx.x * 256 + threadIdx.x;
    if (idx >= 15 * G3) return;
    int c = idx / G3, row = idx % G3;
    float v = b_ih[row];
    if (c < Odim) v += W_ih[row * Odim + c];
    Gt[idx] = v;
}

// gi0[b][row] = b_ih[row] + sum_c relu(x0[b,c]) * W_ih[row,c]
__global__ void prep_gi0(const float* __restrict__ b_ih,
                         const float* __restrict__ W_ih,
                         const float* __restrict__ target,
                         float* __restrict__ gi0) {
    int idx = blockIdx.x * 256 + threadIdx.x;   // 256*6144 total
    int b = idx / G3, row = idx % G3;
    const float* x0 = target + (size_t)b * (Tdim * Odim);  // [b][0][:]
    float s = b_ih[row];
    #pragma unroll
    for (int c = 0; c < Odim; ++c)
        s = fmaf(fmaxf(x0[c], 0.f), W_ih[row * Odim + c], s);
    gi0[idx] = s;
}

// ---------------------------------------------------------------------------
// Kernel A: one GRU step. grid (32 j-tiles, 8 b-tiles), block 256.
// Computes gh = h@W_hh.T for its (32b x 64j) tile x 3 gates, fuses biases,
// gi (table lookup via topi/alive from previous step), gating, h update.
// ---------------------------------------------------------------------------
__global__ __launch_bounds__(256)
void gru_step(const float* __restrict__ h_in, float* __restrict__ h_out,
              const float* __restrict__ W_hh, const float* __restrict__ b_hh,
              const float* __restrict__ Gt, const float* __restrict__ gi0,
              const int* __restrict__ topi, int t) {
    __shared__ __align__(16) float sh[32][36];       // h tile [b][k], pad->36
    __shared__ __align__(16) float sw[3][32][68];    // W tile [g][k][j], pad->68
    __shared__ int s_sel[32];
    __shared__ unsigned long long s_m[4];

    const int tid = threadIdx.x;
    const int tx = tid & 15, ty = tid >> 4;
    const int j0 = blockIdx.x * 64;
    const int b0 = blockIdx.y * 32;

    // ---- alive/sel from previous step's topi (batch-axis inclusive prefix) ----
    if (t > 0) {
        int tp = topi[tid];
        unsigned long long m = __ballot(tp == (Odim - 1));
        if ((tid & 63) == 0) s_m[tid >> 6] = m;
        __syncthreads();
        int w = tid >> 6, l = tid & 63;
        unsigned long long le =
            s_m[w] & ((l == 63) ? ~0ULL : ((1ULL << (l + 1)) - 1ULL));
        bool dead = (le != 0ULL);
        #pragma unroll
        for (int ww = 0; ww < 3; ++ww)
            if (ww < w) dead = dead || (s_m[ww] != 0ULL);
        if (tid >= b0 && tid < b0 + 32) s_sel[tid - b0] = dead ? Odim : tp;
        __syncthreads();
    }

    float acc[3][2][4];
    #pragma unroll
    for (int g = 0; g < 3; ++g)
        #pragma unroll
        for (int i = 0; i < 2; ++i)
            #pragma unroll
            for (int c = 0; c < 4; ++c) acc[g][i][c] = 0.f;

    // staging indices: 256 threads load 32x32 h tile (1 f4 each) and
    // 3 x 64x32 W tiles (2 f4 per gate each)
    const int lrow = tid >> 3;          // 0..31
    const int lcol = (tid & 7) << 2;    // 0,4,...,28
    const float* hP = h_in + (size_t)(b0 + lrow) * Hdim + lcol;

    f4 ph;
    f4 pw[3][2];

    // load + store tile 0
    ph = *(const f4*)hP;
    #pragma unroll
    for (int g = 0; g < 3; ++g)
        #pragma unroll
        for (int r = 0; r < 2; ++r)
            pw[g][r] = *(const f4*)(W_hh +
                (size_t)(g * Hdim + j0 + lrow + r * 32) * Hdim + lcol);
    *(f4*)&sh[lrow][lcol] = ph;
    #pragma unroll
    for (int g = 0; g < 3; ++g)
        #pragma unroll
        for (int r = 0; r < 2; ++r)
            #pragma unroll
            for (int i = 0; i < 4; ++i)
                sw[g][lcol + i][lrow + r * 32] = pw[g][r][i];
    __syncthreads();

    for (int kt = 1; kt <= 64; ++kt) {
        const int kb = kt << 5;
        if (kt < 64) {  // prefetch next tile into registers (overlaps compute)
            ph = *(const f4*)(hP + kb);
            #pragma unroll
            for (int g = 0; g < 3; ++g)
                #pragma unroll
                for (int r = 0; r < 2; ++r)
                    pw[g][r] = *(const f4*)(W_hh +
                        (size_t)(g * Hdim + j0 + lrow + r * 32) * Hdim + kb + lcol);
        }
        #pragma unroll
        for (int k = 0; k < 32; ++k) {
            float a0 = sh[ty * 2 + 0][k];
            float a1 = sh[ty * 2 + 1][k];
            #pragma unroll
            for (int g = 0; g < 3; ++g) {
                f4 w4 = *(const f4*)&sw[g][k][tx * 4];
                #pragma unroll
                for (int c = 0; c < 4; ++c) {
                    acc[g][0][c] = fmaf(a0, w4[c], acc[g][0][c]);
                    acc[g][1][c] = fmaf(a1, w4[c], acc[g][1][c]);
                }
            }
        }
        __syncthreads();
        if (kt < 64) {
            *(f4*)&sh[lrow][lcol] = ph;
            #pragma unroll
            for (int g = 0; g < 3; ++g)
                #pragma unroll
                for (int r = 0; r < 2; ++r)
                    #pragma unroll
                    for (int i = 0; i < 4; ++i)
                        sw[g][lcol + i][lrow + r * 32] = pw[g][r][i];
            __syncthreads();
        }
    }

    // ---- epilogue: gates + h update ----
    #pragma unroll
    for (int i = 0; i < 2; ++i) {
        const int b = b0 + ty * 2 + i;
        const float* gp = (t == 0) ? (gi0 + (size_t)b * G3)
                                   : (Gt + (size_t)s_sel[ty * 2 + i] * G3);
        const int j = j0 + tx * 4;
        f4 hp = *(const f4*)(h_in + (size_t)b * Hdim + j);
        f4 gr = *(const f4*)(gp + j);
        f4 gz = *(const f4*)(gp + Hdim + j);
        f4 gn = *(const f4*)(gp + 2 * Hdim + j);
        f4 br = *(const f4*)(b_hh + j);
        f4 bz = *(const f4*)(b_hh + Hdim + j);
        f4 bn = *(const f4*)(b_hh + 2 * Hdim + j);
        f4 ho;
        #pragma unroll
        for (int c = 0; c < 4; ++c) {
            float ghr = acc[0][i][c] + br[c];
            float ghz = acc[1][i][c] + bz[c];
            float ghn = acc[2][i][c] + bn[c];
            float rr = 1.f / (1.f + expf(-(gr[c] + ghr)));
            float zz = 1.f / (1.f + expf(-(gz[c] + ghz)));
            float nn = tanhf(fmaf(rr, ghn, gn[c]));
            ho[c] = (1.f - zz) * nn + zz * hp[c];
        }
        *(f4*)(h_out + (size_t)b * Hdim + j) = ho;
    }
}

// ---------------------------------------------------------------------------
// Kernel B: logits + argmax (first-max) + log_softmax + topi. grid 256, blk 256.
// Also writes h_final on the last step.
// ---------------------------------------------------------------------------
__global__ __launch_bounds__(256)
void out_step(const float* __restrict__ h, const float* __restrict__ W_out,
              const float* __restrict__ b_out, float* __restrict__ lp,
              int t, int* __restrict__ topi_out, float* __restrict__ hfin) {
    const int b = blockIdx.x;
    const int tid = threadIdx.x;
    __shared__ __align__(16) float shh[Hdim];
    __shared__ float sl[16];

    const float* hb = h + (size_t)b * Hdim;
    f4 v0 = *(const f4*)(hb + 4 * tid);
    f4 v1 = *(const f4*)(hb + 1024 + 4 * tid);
    *(f4*)&shh[4 * tid] = v0;
    *(f4*)&shh[1024 + 4 * tid] = v1;
    __syncthreads();

    const int w = tid >> 6, l = tid & 63;
    for (int o = w; o < Odim; o += 4) {
        const float* wo = W_out + (size_t)o * Hdim;
        float s = 0.f;
        #pragma unroll
        for (int i = 0; i < 32; ++i)
            s = fmaf(shh[l + 64 * i], wo[l + 64 * i], s);
        #pragma unroll
        for (int off = 32; off >= 1; off >>= 1)
            s += __shfl_down(s, off);
        if (l == 0) sl[o] = s + b_out[o];
    }
    __syncthreads();
    if (tid == 0) {
        float m = sl[0];
        int bi = 0;
        #pragma unroll
        for (int o = 1; o < Odim; ++o)
            if (sl[o] > m) { m = sl[o]; bi = o; }   // strict > => first max
        float ssum = 0.f;
        #pragma unroll
        for (int o = 0; o < Odim; ++o) ssum += expf(sl[o] - m);
        topi_out[b] = bi;
        sl[14] = m + logf(ssum);
    }
    __syncthreads();
    if (tid < Odim)
        lp[(size_t)b * (Tdim * Odim) + (size_t)t * Odim + tid] = sl[tid] - sl[14];
    if (hfin) {
        *(f4*)(hfin + (size_t)b * Hdim + 4 * tid) = v0;
        *(f4*)(hfin + (size_t)b * Hdim + 1024 + 4 * tid) = v1;
    }
}

// ---------------------------------------------------------------------------
extern "C" void kernel_launch(void* const* d_in, const int* in_sizes, int n_in,
                              void* d_out, int out_size, void* d_ws, size_t ws_size,
                              hipStream_t stream) {
    const float* enc_hidden = (const float*)d_in[1];   // (1,B,H)
    const float* target     = (const float*)d_in[2];   // (B,T,O)
    const float* W_ih       = (const float*)d_in[3];   // (3H,14)
    const float* W_hh       = (const float*)d_in[4];   // (3H,H)
    const float* b_ih       = (const float*)d_in[5];
    const float* b_hh       = (const float*)d_in[6];
    const float* W_out      = (const float*)d_in[7];   // (14,H)
    const float* b_out      = (const float*)d_in[8];

    float* out  = (float*)d_out;
    float* lp   = out;                              // (B,T,O)
    float* hfin = out + (size_t)Bdim * Tdim * Odim; // (1,B,H)

    float* ws    = (float*)d_ws;
    float* hbuf0 = ws;                       // B*H
    float* hbuf1 = ws + 524288;              // B*H
    float* Gt    = ws + 1048576;             // 15*6144
    float* gi0   = Gt + 15 * G3;             // B*6144
    int*   topi  = (int*)(gi0 + (size_t)Bdim * G3);

    prep_gtable<<<(15 * G3 + 255) / 256, 256, 0, stream>>>(b_ih, W_ih, Gt);
    prep_gi0<<<(Bdim * G3) / 256, 256, 0, stream>>>(b_ih, W_ih, target, gi0);

    for (int t = 0; t < Tdim; ++t) {
        const float* hin = (t == 0) ? enc_hidden : ((t & 1) ? hbuf0 : hbuf1);
        float* hout = (t & 1) ? hbuf1 : hbuf0;
        gru_step<<<dim3(32, 8), 256, 0, stream>>>(hin, hout, W_hh, b_hh,
                                                  Gt, gi0, topi, t);
        out_step<<<256, 256, 0, stream>>>(hout, W_out, b_out, lp, t, topi,
                                          (t == Tdim - 1) ? hfin : nullptr);
    }
}

// Round 3
// 26915.744 us; speedup vs baseline: 5.0463x; 5.0463x over previous
//
#include <hip/hip_runtime.h>
#include <math.h>

typedef float f4 __attribute__((ext_vector_type(4)));
typedef _Float16 f16x8 __attribute__((ext_vector_type(8)));
typedef int i4 __attribute__((ext_vector_type(4)));

#define Hdim 2048
#define Bdim 256
#define Tdim 512
#define Odim 14
#define G3   6144   // 3*Hdim

// ---------------------------------------------------------------------------
// Prep kernels (once per launch)
// ---------------------------------------------------------------------------

__global__ void prep_gtable(const float* __restrict__ b_ih,
                            const float* __restrict__ W_ih,
                            float* __restrict__ Gt) {
    int idx = blockIdx.x * 256 + threadIdx.x;
    if (idx >= 15 * G3) return;
    int c = idx / G3, row = idx % G3;
    float v = b_ih[row];
    if (c < Odim) v += W_ih[row * Odim + c];
    Gt[idx] = v;
}

__global__ void prep_gi0(const float* __restrict__ b_ih,
                         const float* __restrict__ W_ih,
                         const float* __restrict__ target,
                         float* __restrict__ gi0) {
    int idx = blockIdx.x * 256 + threadIdx.x;
    int b = idx / G3, row = idx % G3;
    const float* x0 = target + (size_t)b * (Tdim * Odim);
    float s = b_ih[row];
    #pragma unroll
    for (int c = 0; c < Odim; ++c)
        s = fmaf(fmaxf(x0[c], 0.f), W_ih[row * Odim + c], s);
    gi0[idx] = s;
}

// W_hh (6144x2048 f32) -> hi/lo fp16 frag-major: [nt][kb][lane][8]
// n = nt*16 + (lane&15), k = kb*32 + (lane>>4)*8 + j
__global__ void prep_Bpack(const float* __restrict__ W,
                           _Float16* __restrict__ Bh, _Float16* __restrict__ Bl) {
    int idx = blockIdx.x * 256 + threadIdx.x;  // 6144*256 threads
    int n = idx >> 8, kc = idx & 255;
    const float* src = W + (size_t)n * Hdim + kc * 8;
    int kb = kc >> 2, q = kc & 3;
    int lane = (n & 15) + 16 * q;
    int nt = n >> 4;
    f16x8 vh, vl;
    #pragma unroll
    for (int j = 0; j < 8; ++j) {
        float w = src[j];
        _Float16 h = (_Float16)w;
        vh[j] = h;
        vl[j] = (_Float16)(w - (float)h);
    }
    size_t off = (((size_t)nt * 64 + kb) * 64 + lane) * 8;
    *(f16x8*)(Bh + off) = vh;
    *(f16x8*)(Bl + off) = vl;
}

// enc_hidden (256x2048 f32) -> hi/lo fp16 frag-major: [mt][kb][lane][8]
__global__ void prep_A0(const float* __restrict__ h0,
                        _Float16* __restrict__ Ah, _Float16* __restrict__ Al) {
    int idx = blockIdx.x * 256 + threadIdx.x;  // 256*256 threads
    int m = idx >> 8, kc = idx & 255;
    const float* src = h0 + (size_t)m * Hdim + kc * 8;
    int kb = kc >> 2, q = kc & 3;
    int lane = (m & 15) + 16 * q;
    int mt = m >> 4;
    f16x8 vh, vl;
    #pragma unroll
    for (int j = 0; j < 8; ++j) {
        float w = src[j];
        _Float16 h = (_Float16)w;
        vh[j] = h;
        vl[j] = (_Float16)(w - (float)h);
    }
    size_t off = (((size_t)mt * 64 + kb) * 64 + lane) * 8;
    *(f16x8*)(Ah + off) = vh;
    *(f16x8*)(Al + off) = vl;
}

// ---------------------------------------------------------------------------
// Kernel 1: hi/lo fp16 MFMA GEMM  C[256 x 6144] = A[256x2048] * W[6144x2048]^T
// C = Ah*Wh + Ah*Wl + Al*Wh  (fp32-equivalent precision)
// grid (64 N-tiles of 96, 4 K-slices of 512); 256 thr = 4 waves.
// Wave w: rows [w*64, w*64+64) x all 96 N of the tile (mf=4 x nf=6 frags).
// ---------------------------------------------------------------------------
__global__ __launch_bounds__(256, 1)
void gemm_step(const _Float16* __restrict__ Ah, const _Float16* __restrict__ Al,
               const _Float16* __restrict__ Bh, const _Float16* __restrict__ Bl,
               float* __restrict__ Cpart) {
    // [buf][ hi: 24 blk x 64 lane x 8 | lo: same ]  (blk = ntl*4 + kbl)
    __shared__ _Float16 sB[2][24576];

    const int tid = threadIdx.x;
    const int wave = tid >> 6, lane = tid & 63;
    const int nt0 = blockIdx.x * 6;
    const int kb0 = blockIdx.y * 16;   // 16 kb-blocks (512 k) per slice

    f4 acc[4][6];
    #pragma unroll
    for (int mf = 0; mf < 4; ++mf)
        #pragma unroll
        for (int nf = 0; nf < 6; ++nf) acc[mf][nf] = (f4)0.f;

    i4 rh[6], rl[6];

    // stage chunk 0 (4 kb-blocks, hi+lo)
    #pragma unroll
    for (int i = 0; i < 6; ++i) {
        int e = i * 256 + tid, blk = e >> 6, l = e & 63;
        int ntl = blk >> 2, kbl = blk & 3;
        size_t off = (((size_t)(nt0 + ntl) * 64) + kb0 + kbl) * 512 + l * 8;
        rh[i] = *(const i4*)(Bh + off);
        rl[i] = *(const i4*)(Bl + off);
    }
    #pragma unroll
    for (int i = 0; i < 6; ++i) {
        ((i4*)sB[0])[i * 256 + tid] = rh[i];
        ((i4*)sB[0])[1536 + i * 256 + tid] = rl[i];
    }
    __syncthreads();

    for (int c = 0; c < 4; ++c) {
        const int buf = c & 1;
        if (c < 3) {  // prefetch chunk c+1 into registers
            #pragma unroll
            for (int i = 0; i < 6; ++i) {
                int e = i * 256 + tid, blk = e >> 6, l = e & 63;
                int ntl = blk >> 2, kbl = blk & 3;
                size_t off = (((size_t)(nt0 + ntl) * 64) + kb0 + (c + 1) * 4 + kbl) * 512 + l * 8;
                rh[i] = *(const i4*)(Bh + off);
                rl[i] = *(const i4*)(Bl + off);
            }
        }
        #pragma unroll
        for (int kbl = 0; kbl < 4; ++kbl) {
            const int kb = kb0 + c * 4 + kbl;
            f16x8 ah[4], al[4], bh[6], bl[6];
            #pragma unroll
            for (int mf = 0; mf < 4; ++mf) {
                size_t off = (((size_t)(wave * 4 + mf) * 64 + kb) * 64 + lane) * 8;
                ah[mf] = *(const f16x8*)(Ah + off);
                al[mf] = *(const f16x8*)(Al + off);
            }
            #pragma unroll
            for (int nf = 0; nf < 6; ++nf) {
                bh[nf] = *(const f16x8*)(&sB[buf][(nf * 4 + kbl) * 512 + lane * 8]);
                bl[nf] = *(const f16x8*)(&sB[buf][12288 + (nf * 4 + kbl) * 512 + lane * 8]);
            }
            #pragma unroll
            for (int mf = 0; mf < 4; ++mf)
                #pragma unroll
                for (int nf = 0; nf < 6; ++nf) {
                    acc[mf][nf] = __builtin_amdgcn_mfma_f32_16x16x32_f16(
                        ah[mf], bh[nf], acc[mf][nf], 0, 0, 0);
                    acc[mf][nf] = __builtin_amdgcn_mfma_f32_16x16x32_f16(
                        ah[mf], bl[nf], acc[mf][nf], 0, 0, 0);
                    acc[mf][nf] = __builtin_amdgcn_mfma_f32_16x16x32_f16(
                        al[mf], bh[nf], acc[mf][nf], 0, 0, 0);
                }
        }
        if (c < 3) {  // store prefetched chunk into the other buffer
            #pragma unroll
            for (int i = 0; i < 6; ++i) {
                ((i4*)sB[buf ^ 1])[i * 256 + tid] = rh[i];
                ((i4*)sB[buf ^ 1])[1536 + i * 256 + tid] = rl[i];
            }
            __syncthreads();
        }
    }

    // store partials: C/D frag: col(N)=lane&15, row(M)=(lane>>4)*4+q
    const size_t base = (size_t)blockIdx.y * 256 * G3;
    #pragma unroll
    for (int mf = 0; mf < 4; ++mf) {
        int mrow = wave * 64 + mf * 16 + (lane >> 4) * 4;
        #pragma unroll
        for (int nf = 0; nf < 6; ++nf) {
            int n = (nt0 + nf) * 16 + (lane & 15);
            #pragma unroll
            for (int q = 0; q < 4; ++q)
                Cpart[base + (size_t)(mrow + q) * G3 + n] = acc[mf][nf][q];
        }
    }
}

// ---------------------------------------------------------------------------
// Kernel 2: fused epilogue. grid 256 (wg = batch row b), 256 thr.
// Sums 4 K-partials + b_hh + gi (table via topi/alive), gates, writes h fp32
// + hi/lo fp16 A-pack, then logits/argmax/log_softmax/topi (+h_final).
// ---------------------------------------------------------------------------
__global__ __launch_bounds__(256)
void fused_out(const float* __restrict__ hprev, float* __restrict__ hnew,
               const float* __restrict__ Cpart, const float* __restrict__ Gt,
               const float* __restrict__ gi0, const float* __restrict__ b_hh,
               const float* __restrict__ W_out, const float* __restrict__ b_out,
               _Float16* __restrict__ Ah, _Float16* __restrict__ Al,
               const int* __restrict__ topi_in, int* __restrict__ topi_out,
               float* __restrict__ lp, float* __restrict__ hfin, int t) {
    const int b = blockIdx.x;
    const int tid = threadIdx.x;
    __shared__ __align__(16) float sh[Hdim];
    __shared__ float sl[16];
    __shared__ int s_sel;
    __shared__ unsigned long long s_m[4];

    if (t > 0) {
        int tp = topi_in[tid];
        unsigned long long m = __ballot(tp == (Odim - 1));
        if ((tid & 63) == 0) s_m[tid >> 6] = m;
        __syncthreads();
        if (tid == 0) {
            int bw = b >> 6, bl = b & 63;
            unsigned long long le =
                s_m[bw] & ((bl == 63) ? ~0ULL : ((1ULL << (bl + 1)) - 1ULL));
            bool dead = (le != 0ULL);
            for (int w = 0; w < bw; ++w) dead = dead || (s_m[w] != 0ULL);
            s_sel = dead ? Odim : topi_in[b];
        }
        __syncthreads();
    }
    const float* gp = (t == 0) ? (gi0 + (size_t)b * G3)
                               : (Gt + (size_t)s_sel * G3);

    const int j0 = tid * 8;
    float hn[8];
    {
        float gsum[3][8];
        #pragma unroll
        for (int g = 0; g < 3; ++g) {
            f4 s0 = *(const f4*)(b_hh + g * Hdim + j0);
            f4 s1 = *(const f4*)(b_hh + g * Hdim + j0 + 4);
            #pragma unroll
            for (int c = 0; c < 4; ++c) { gsum[g][c] = s0[c]; gsum[g][4 + c] = s1[c]; }
            #pragma unroll
            for (int ks = 0; ks < 4; ++ks) {
                const float* cp = Cpart + ((size_t)ks * Bdim + b) * G3 + g * Hdim + j0;
                f4 p0 = *(const f4*)cp;
                f4 p1 = *(const f4*)(cp + 4);
                #pragma unroll
                for (int c = 0; c < 4; ++c) { gsum[g][c] += p0[c]; gsum[g][4 + c] += p1[c]; }
            }
        }
        f4 hp0 = *(const f4*)(hprev + (size_t)b * Hdim + j0);
        f4 hp1 = *(const f4*)(hprev + (size_t)b * Hdim + j0 + 4);
        f4 gr0 = *(const f4*)(gp + j0),            gr1 = *(const f4*)(gp + j0 + 4);
        f4 gz0 = *(const f4*)(gp + Hdim + j0),     gz1 = *(const f4*)(gp + Hdim + j0 + 4);
        f4 gn0 = *(const f4*)(gp + 2 * Hdim + j0), gn1 = *(const f4*)(gp + 2 * Hdim + j0 + 4);
        #pragma unroll
        for (int c = 0; c < 8; ++c) {
            float gi_r = (c < 4) ? gr0[c] : gr1[c - 4];
            float gi_z = (c < 4) ? gz0[c] : gz1[c - 4];
            float gi_n = (c < 4) ? gn0[c] : gn1[c - 4];
            float hp   = (c < 4) ? hp0[c] : hp1[c - 4];
            float rr = 1.f / (1.f + expf(-(gi_r + gsum[0][c])));
            float zz = 1.f / (1.f + expf(-(gi_z + gsum[1][c])));
            float nn = tanhf(fmaf(rr, gsum[2][c], gi_n));
            hn[c] = (1.f - zz) * nn + zz * hp;
        }
    }
    f4 o0, o1;
    #pragma unroll
    for (int c = 0; c < 4; ++c) { o0[c] = hn[c]; o1[c] = hn[4 + c]; }
    *(f4*)(hnew + (size_t)b * Hdim + j0) = o0;
    *(f4*)(hnew + (size_t)b * Hdim + j0 + 4) = o1;
    {   // hi/lo fp16 A-pack: mt=b>>4, kb=tid>>2, q=tid&3, lane=(b&15)+16q
        f16x8 vh, vl;
        #pragma unroll
        for (int c = 0; c < 8; ++c) {
            _Float16 hh = (_Float16)hn[c];
            vh[c] = hh;
            vl[c] = (_Float16)(hn[c] - (float)hh);
        }
        int kb = tid >> 2, q = tid & 3;
        int lane = (b & 15) + 16 * q, mt = b >> 4;
        size_t off = (((size_t)mt * 64 + kb) * 64 + lane) * 8;
        *(f16x8*)(Ah + off) = vh;
        *(f16x8*)(Al + off) = vl;
    }
    *(f4*)(sh + j0) = o0;
    *(f4*)(sh + j0 + 4) = o1;
    __syncthreads();

    const int w = tid >> 6, l = tid & 63;
    for (int o = w; o < Odim; o += 4) {
        const float* wo = W_out + (size_t)o * Hdim;
        float s = 0.f;
        #pragma unroll
        for (int i = 0; i < 32; ++i)
            s = fmaf(sh[l + 64 * i], wo[l + 64 * i], s);
        #pragma unroll
        for (int off = 32; off >= 1; off >>= 1)
            s += __shfl_down(s, off);
        if (l == 0) sl[o] = s + b_out[o];
    }
    __syncthreads();
    if (tid == 0) {
        float m = sl[0]; int bi = 0;
        #pragma unroll
        for (int o = 1; o < Odim; ++o)
            if (sl[o] > m) { m = sl[o]; bi = o; }   // strict > = first max
        float ssum = 0.f;
        #pragma unroll
        for (int o = 0; o < Odim; ++o) ssum += expf(sl[o] - m);
        topi_out[b] = bi;
        sl[14] = m + logf(ssum);
    }
    __syncthreads();
    if (tid < Odim)
        lp[(size_t)b * (Tdim * Odim) + (size_t)t * Odim + tid] = sl[tid] - sl[14];
    if (hfin) {
        *(f4*)(hfin + (size_t)b * Hdim + j0) = o0;
        *(f4*)(hfin + (size_t)b * Hdim + j0 + 4) = o1;
    }
}

// ---------------------------------------------------------------------------
extern "C" void kernel_launch(void* const* d_in, const int* in_sizes, int n_in,
                              void* d_out, int out_size, void* d_ws, size_t ws_size,
                              hipStream_t stream) {
    const float* enc_hidden = (const float*)d_in[1];
    const float* target     = (const float*)d_in[2];
    const float* W_ih       = (const float*)d_in[3];
    const float* W_hh       = (const float*)d_in[4];
    const float* b_ih       = (const float*)d_in[5];
    const float* b_hh       = (const float*)d_in[6];
    const float* W_out      = (const float*)d_in[7];
    const float* b_out      = (const float*)d_in[8];

    float* out  = (float*)d_out;
    float* lp   = out;
    float* hfin = out + (size_t)Bdim * Tdim * Odim;

    float* ws    = (float*)d_ws;
    float* hb0   = ws;                        // 524288
    float* hb1   = hb0 + 524288;              // 524288
    float* Gt    = hb1 + 524288;              // 92160
    float* gi0   = Gt + 15 * G3;              // 1572864
    float* Cpart = gi0 + (size_t)Bdim * G3;   // 4*1572864
    _Float16* Ah = (_Float16*)(Cpart + 4 * (size_t)Bdim * G3);  // 524288 halves
    _Float16* Al = Ah + (size_t)Bdim * Hdim;                    // 524288
    _Float16* Bh = Al + (size_t)Bdim * Hdim;                    // 12582912
    _Float16* Bl = Bh + (size_t)G3 * Hdim;                      // 12582912
    int* topibuf = (int*)(Bl + (size_t)G3 * Hdim);              // 512 ints

    prep_gtable<<<(15 * G3 + 255) / 256, 256, 0, stream>>>(b_ih, W_ih, Gt);
    prep_gi0<<<(Bdim * G3) / 256, 256, 0, stream>>>(b_ih, W_ih, target, gi0);
    prep_Bpack<<<(G3 * 256) / 256, 256, 0, stream>>>(W_hh, Bh, Bl);
    prep_A0<<<(Bdim * 256) / 256, 256, 0, stream>>>(enc_hidden, Ah, Al);

    for (int t = 0; t < Tdim; ++t) {
        float* hnew = (t & 1) ? hb1 : hb0;
        const float* hprev = (t == 0) ? enc_hidden : ((t & 1) ? hb0 : hb1);
        int* tin  = topibuf + ((t + 1) & 1) * 256;
        int* tout = topibuf + (t & 1) * 256;
        gemm_step<<<dim3(64, 4), 256, 0, stream>>>(Ah, Al, Bh, Bl, Cpart);
        fused_out<<<256, 256, 0, stream>>>(hprev, hnew, Cpart, Gt, gi0, b_hh,
                                           W_out, b_out, Ah, Al, tin, tout, lp,
                                           (t == Tdim - 1) ? hfin : nullptr, t);
    }
}